// Round 11
// baseline (52.057 us; speedup 1.0000x reference)
//
#include <hip/hip_runtime.h>
#include <hip/hip_bf16.h>

#define IN_F 8192
#define OUT_F 8192
#define NROWS 128
#define CB 256
#define NSL 8                  // split-K slices
#define KSLICE (IN_F / NSL)    // 1024
#define NTB 128                // n-tile per block
#define QC (IN_F / 8)          // 1024 dwords per Qidxs row

using bf8   = __attribute__((ext_vector_type(8))) short;  // 8 bf16 (4 VGPRs)
using f32x4 = __attribute__((ext_vector_type(4))) float;  // 4 fp32 accum

__device__ inline float bf2f(unsigned int u) {
    union { unsigned int i; float f; } v; v.i = u << 16; return v.f;
}
__device__ inline unsigned short f2bf(float f) {
    __hip_bfloat16 h = __float2bfloat16(f);
    return *reinterpret_cast<unsigned short*>(&h);
}
__device__ inline void unpack8(uint4 v, float* f) {
    f[0] = bf2f(v.x & 0xffffu); f[1] = bf2f(v.x >> 16);
    f[2] = bf2f(v.y & 0xffffu); f[3] = bf2f(v.y >> 16);
    f[4] = bf2f(v.z & 0xffffu); f[5] = bf2f(v.z >> 16);
    f[6] = bf2f(v.w & 0xffffu); f[7] = bf2f(v.w >> 16);
}

#define FWHT_SCALE 0.011048543456039806f  // 1/sqrt(8192)

// ---------------- FWHT-4096 on 256 threads x 16 elems ----------------
// Levels: bits 0-3 in-reg, exch, bits 4-7, exch, bits 8-11, exch to linear.
// lds: float[4160], stride 260 (mod4=0 for b128 align; banks <=2-way).
#define FWHT16(v)                                                         \
    _Pragma("unroll")                                                     \
    for (int hb = 0; hb < 4; ++hb) {                                      \
        const int hh = 1 << hb;                                           \
        _Pragma("unroll")                                                 \
        for (int j = 0; j < 16; ++j)                                      \
            if (!(j & hh)) {                                              \
                float a_ = v[j], b_ = v[j | hh];                          \
                v[j] = a_ + b_; v[j | hh] = a_ - b_;                      \
            }                                                             \
    }

__device__ inline void fwht4096(float* v, float* lds, int t) {
    FWHT16(v)                                   // bits 0-3 (e)
    // exch1: (e, t) -> holder (e = t&15, u = (t>>4)*16 + i)
#pragma unroll
    for (int e = 0; e < 16; ++e) lds[e * 260 + t] = v[e];
    __syncthreads();
    {
        const int base = (t & 15) * 260 + (t >> 4) * 16;
#pragma unroll
        for (int q = 0; q < 4; ++q) {
            float4 f = *reinterpret_cast<const float4*>(&lds[base + q * 4]);
            v[q * 4 + 0] = f.x; v[q * 4 + 1] = f.y;
            v[q * 4 + 2] = f.z; v[q * 4 + 3] = f.w;
        }
    }
    FWHT16(v)                                   // bits 4-7 (i)
    __syncthreads();
    // exch2: store (e,i,ub) at e*260 + i*16 + ub; holder (e, i fixed, ub 0..15)
    {
        const int e = t & 15, ub = t >> 4;
#pragma unroll
        for (int i = 0; i < 16; ++i) lds[e * 260 + i * 16 + ub] = v[i];
    }
    __syncthreads();
    {
        const int e = t & 15, i = t >> 4;
#pragma unroll
        for (int ub = 0; ub < 16; ++ub) v[ub] = lds[e * 260 + i * 16 + ub];
    }
    FWHT16(v)                                   // bits 8-11 (ub)
    __syncthreads();
    // exch3: back to linear j = ub*256 + i*16 + e; holder (ub = t>>4, i = t&15)
    {
        const int e = t & 15, i = t >> 4;
#pragma unroll
        for (int ub = 0; ub < 16; ++ub) lds[ub * 260 + i * 16 + e] = v[ub];
    }
    __syncthreads();
    {
        const int base = (t >> 4) * 260 + (t & 15) * 16;
#pragma unroll
        for (int q = 0; q < 4; ++q) {
            float4 f = *reinterpret_cast<const float4*>(&lds[base + q * 4]);
            v[q * 4 + 0] = f.x; v[q * 4 + 1] = f.y;
            v[q * 4 + 2] = f.z; v[q * 4 + 3] = f.w;
        }
    }
}

// ---- Kernel A: xt = fwht(input/scaleWH*SU), MFMA-tiled bf16, grid (128,2) --
// Tiled layout: elem (r,k) at ((r>>4)*256 + (k>>5))*512 + ((k&31)>>3)*128
//               + (r&15)*8 + (k&7)   [ushort units]
__global__ __launch_bounds__(256) void k_pre4(const float* __restrict__ in,
                                              const float* __restrict__ scaleWH,
                                              const float* __restrict__ SU,
                                              unsigned short* __restrict__ xt) {
    __shared__ float lds[4160];
    const int r = blockIdx.x, h = blockIdx.y, t = threadIdx.x;
    float v[16];
    const float4* xp = reinterpret_cast<const float4*>(in + (size_t)r * IN_F);
    const float4* sp = reinterpret_cast<const float4*>(scaleWH);
    const float4* up = reinterpret_cast<const float4*>(SU);
#pragma unroll
    for (int q = 0; q < 4; ++q) {
        float4 xl = xp[t * 4 + q],       sl = sp[t * 4 + q],       ul = up[t * 4 + q];
        float4 xh = xp[1024 + t * 4 + q], sh = sp[1024 + t * 4 + q], uh = up[1024 + t * 4 + q];
        float lo0 = xl.x / sl.x * ul.x, hi0 = xh.x / sh.x * uh.x;
        float lo1 = xl.y / sl.y * ul.y, hi1 = xh.y / sh.y * uh.y;
        float lo2 = xl.z / sl.z * ul.z, hi2 = xh.z / sh.z * uh.z;
        float lo3 = xl.w / sl.w * ul.w, hi3 = xh.w / sh.w * uh.w;
        v[q * 4 + 0] = h ? lo0 - hi0 : lo0 + hi0;
        v[q * 4 + 1] = h ? lo1 - hi1 : lo1 + hi1;
        v[q * 4 + 2] = h ? lo2 - hi2 : lo2 + hi2;
        v[q * 4 + 3] = h ? lo3 - hi3 : lo3 + hi3;
    }
    fwht4096(v, lds, t);
    // thread holds j = (t>>4)*256 + (t&15)*16 + e; k = h*4096 + j
    const int ub = t >> 4, i = t & 15;
    const int kblk = h * 128 + ub * 8 + (i >> 1);
    const size_t base = ((size_t)(r >> 4) * 256 + kblk) * 512 + (size_t)(r & 15) * 8;
#pragma unroll
    for (int half = 0; half < 2; ++half) {
        unsigned int w[4];
#pragma unroll
        for (int p = 0; p < 4; ++p) {
            unsigned int lo = f2bf(v[half * 8 + 2 * p]     * FWHT_SCALE);
            unsigned int hi = f2bf(v[half * 8 + 2 * p + 1] * FWHT_SCALE);
            w[p] = lo | (hi << 16);
        }
        const int oct = (i & 1) * 2 + half;
        *reinterpret_cast<uint4*>(xt + base + oct * 128) = make_uint4(w[0], w[1], w[2], w[3]);
    }
}

// ---- Kernel B: GEMM, reg-staged Qidxs chunks (T14), NTB=128 ----
// grid (64, NSL); 256 thr = 4 waves (2x2); block tile 128x128; K-step 32.
// Chunk = 16 iters: load chunk c+1 Qidxs to regs early, compute chunk c
// (all ds_reads freely schedulable - no LDS writes in flight), barrier,
// ds_write c+1 (vmcnt waits on loads issued a full chunk ago), barrier.
__global__ __launch_bounds__(256, 2) void k_gemm7(
        const unsigned short* __restrict__ xt,
        const int* __restrict__ Qidxs,
        const float* __restrict__ cb,
        const float* __restrict__ wscale,
        unsigned short* __restrict__ pout) {
    __shared__ __align__(16) unsigned short cbl[CB][8];   // 4 KB
    __shared__ __align__(16) int Qlds[128 * 64];          // 32 KB
    const int tid = threadIdx.x;
    const int wave = tid >> 6, lane = tid & 63;
    const int wr = wave >> 1, wc = wave & 1;
    const int lr = lane & 15, lk8 = lane >> 4;
    const int n0 = blockIdx.x * NTB;
    const int ks0 = blockIdx.y * KSLICE;
    const int ksb = ks0 >> 5;
    const int c0 = ks0 >> 3;

    const int srow = tid >> 4;          // 0..15
    const int scg  = tid & 15;
    const int scgs = scg ^ srow;        // col-group swizzle by (row & 15)

    int4 sreg[8];
#define LOADQ(CH)                                                             \
    {                                                                         \
        _Pragma("unroll")                                                     \
        for (int j = 0; j < 8; ++j)                                           \
            sreg[j] = *reinterpret_cast<const int4*>(                         \
                Qidxs + (size_t)(n0 + j * 16 + srow) * QC + c0 + (CH) * 64 + scg * 4); \
    }
#define WRITEQ()                                                              \
    {                                                                         \
        _Pragma("unroll")                                                     \
        for (int j = 0; j < 8; ++j)                                           \
            *reinterpret_cast<int4*>(&Qlds[(j * 16 + srow) * 64 + scgs * 4]) = sreg[j]; \
    }

    LOADQ(0)
    const float wsc = wscale[0];
    for (int e = tid; e < CB * 8; e += 256) cbl[e >> 3][e & 7] = f2bf(cb[e] * wsc);

    f32x4 acc[4][4];
#pragma unroll
    for (int mt = 0; mt < 4; ++mt)
#pragma unroll
        for (int nt = 0; nt < 4; ++nt) acc[mt][nt] = (f32x4){0.f, 0.f, 0.f, 0.f};

    const unsigned short* xw = xt + ((size_t)(wr * 4) * 256 + ksb) * 512 + lane * 8;

    WRITEQ()
    __syncthreads();          // cbl + chunk 0 visible
    LOADQ(1)                  // chunk 1 in flight across chunk 0 compute

#define CHUNK(CH)                                                             \
    _Pragma("unroll")                                                         \
    for (int itc = 0; itc < 16; ++itc) {                                      \
        const int it = (CH) * 16 + itc;                                       \
        const int qcol = ((itc ^ lr) << 2) + lk8;                             \
        const int qv0 = Qlds[(wc * 64 +  0 + lr) * 64 + qcol];                \
        const int qv1 = Qlds[(wc * 64 + 16 + lr) * 64 + qcol];                \
        const int qv2 = Qlds[(wc * 64 + 32 + lr) * 64 + qcol];                \
        const int qv3 = Qlds[(wc * 64 + 48 + lr) * 64 + qcol];                \
        bf8 a0 = *reinterpret_cast<const bf8*>(xw + ((size_t)(0 * 256) + it) * 512); \
        bf8 a1 = *reinterpret_cast<const bf8*>(xw + ((size_t)(1 * 256) + it) * 512); \
        bf8 a2 = *reinterpret_cast<const bf8*>(xw + ((size_t)(2 * 256) + it) * 512); \
        bf8 a3 = *reinterpret_cast<const bf8*>(xw + ((size_t)(3 * 256) + it) * 512); \
        bf8 b0 = *(const bf8*)&cbl[qv0][0];                                   \
        bf8 b1 = *(const bf8*)&cbl[qv1][0];                                   \
        bf8 b2 = *(const bf8*)&cbl[qv2][0];                                   \
        bf8 b3 = *(const bf8*)&cbl[qv3][0];                                   \
        acc[0][0] = __builtin_amdgcn_mfma_f32_16x16x32_bf16(a0, b0, acc[0][0], 0, 0, 0); \
        acc[0][1] = __builtin_amdgcn_mfma_f32_16x16x32_bf16(a0, b1, acc[0][1], 0, 0, 0); \
        acc[0][2] = __builtin_amdgcn_mfma_f32_16x16x32_bf16(a0, b2, acc[0][2], 0, 0, 0); \
        acc[0][3] = __builtin_amdgcn_mfma_f32_16x16x32_bf16(a0, b3, acc[0][3], 0, 0, 0); \
        acc[1][0] = __builtin_amdgcn_mfma_f32_16x16x32_bf16(a1, b0, acc[1][0], 0, 0, 0); \
        acc[1][1] = __builtin_amdgcn_mfma_f32_16x16x32_bf16(a1, b1, acc[1][1], 0, 0, 0); \
        acc[1][2] = __builtin_amdgcn_mfma_f32_16x16x32_bf16(a1, b2, acc[1][2], 0, 0, 0); \
        acc[1][3] = __builtin_amdgcn_mfma_f32_16x16x32_bf16(a1, b3, acc[1][3], 0, 0, 0); \
        acc[2][0] = __builtin_amdgcn_mfma_f32_16x16x32_bf16(a2, b0, acc[2][0], 0, 0, 0); \
        acc[2][1] = __builtin_amdgcn_mfma_f32_16x16x32_bf16(a2, b1, acc[2][1], 0, 0, 0); \
        acc[2][2] = __builtin_amdgcn_mfma_f32_16x16x32_bf16(a2, b2, acc[2][2], 0, 0, 0); \
        acc[2][3] = __builtin_amdgcn_mfma_f32_16x16x32_bf16(a2, b3, acc[2][3], 0, 0, 0); \
        acc[3][0] = __builtin_amdgcn_mfma_f32_16x16x32_bf16(a3, b0, acc[3][0], 0, 0, 0); \
        acc[3][1] = __builtin_amdgcn_mfma_f32_16x16x32_bf16(a3, b1, acc[3][1], 0, 0, 0); \
        acc[3][2] = __builtin_amdgcn_mfma_f32_16x16x32_bf16(a3, b2, acc[3][2], 0, 0, 0); \
        acc[3][3] = __builtin_amdgcn_mfma_f32_16x16x32_bf16(a3, b3, acc[3][3], 0, 0, 0); \
    }

    CHUNK(0)
    __syncthreads();          // all waves done reading chunk 0
    WRITEQ()                  // vmcnt waits loads issued ~full chunk ago
    __syncthreads();          // chunk 1 visible
    CHUNK(1)
#undef CHUNK
#undef LOADQ
#undef WRITEQ

    // epilogue: C/D col=lane&15, row=(lane>>4)*4+reg; bf16 partial store
    unsigned short* ps = pout + (size_t)blockIdx.y * (NROWS * OUT_F);
#pragma unroll
    for (int mt = 0; mt < 4; ++mt) {
        const int row = wr * 64 + mt * 16 + lk8 * 4;
#pragma unroll
        for (int nt = 0; nt < 4; ++nt) {
            const int col = n0 + wc * 64 + nt * 16 + lr;
#pragma unroll
            for (int r2 = 0; r2 < 4; ++r2)
                ps[(size_t)(row + r2) * OUT_F + col] = f2bf(acc[mt][nt][r2]);
        }
    }
}

// ---- Kernel C: out = fwht(sum_slices)*SV + bias, grid (128,2), f32 out ----
__global__ __launch_bounds__(256) void k_post4(const unsigned short* __restrict__ pin,
                                               const float* __restrict__ SV,
                                               const float* __restrict__ bias,
                                               float* __restrict__ out) {
    __shared__ float lds[4160];
    const int r = blockIdx.x, h = blockIdx.y, t = threadIdx.x;
    float lo[16], hi[16], v[16];
#pragma unroll
    for (int j = 0; j < 16; ++j) { lo[j] = 0.f; hi[j] = 0.f; }
#pragma unroll 1
    for (int sl = 0; sl < NSL; ++sl) {
        const uint4* pl = reinterpret_cast<const uint4*>(
            pin + (size_t)sl * NROWS * OUT_F + (size_t)r * OUT_F + t * 16);
        const uint4* ph = reinterpret_cast<const uint4*>(
            pin + (size_t)sl * NROWS * OUT_F + (size_t)r * OUT_F + 4096 + t * 16);
        float a[8], b[8];
        unpack8(pl[0], a); unpack8(pl[1], b);
#pragma unroll
        for (int j = 0; j < 8; ++j) { lo[j] += a[j]; lo[8 + j] += b[j]; }
        unpack8(ph[0], a); unpack8(ph[1], b);
#pragma unroll
        for (int j = 0; j < 8; ++j) { hi[j] += a[j]; hi[8 + j] += b[j]; }
    }
#pragma unroll
    for (int j = 0; j < 16; ++j) v[j] = h ? lo[j] - hi[j] : lo[j] + hi[j];
    fwht4096(v, lds, t);
    // thread holds j = (t>>4)*256 + (t&15)*16 + e; out col = h*4096 + j
    const int cb4 = (h * 4096 + (t >> 4) * 256 + (t & 15) * 16) >> 2;
    const float4* svp = reinterpret_cast<const float4*>(SV);
    const float4* bip = reinterpret_cast<const float4*>(bias);
    float4* op = reinterpret_cast<float4*>(out + (size_t)r * OUT_F);
#pragma unroll
    for (int q = 0; q < 4; ++q) {
        float4 sv = svp[cb4 + q], bi = bip[cb4 + q], o;
        o.x = v[q * 4 + 0] * FWHT_SCALE * sv.x + bi.x;
        o.y = v[q * 4 + 1] * FWHT_SCALE * sv.y + bi.y;
        o.z = v[q * 4 + 2] * FWHT_SCALE * sv.z + bi.z;
        o.w = v[q * 4 + 3] * FWHT_SCALE * sv.w + bi.w;
        op[cb4 + q] = o;
    }
}

extern "C" void kernel_launch(void* const* d_in, const int* in_sizes, int n_in,
                              void* d_out, int out_size, void* d_ws, size_t ws_size,
                              hipStream_t stream) {
    const float* in      = (const float*)d_in[0];
    const int*   Qidxs   = (const int*)d_in[1];
    const float* cb      = (const float*)d_in[2];
    const float* scaleWH = (const float*)d_in[3];
    const float* SU      = (const float*)d_in[4];
    const float* SV      = (const float*)d_in[5];
    const float* wscale  = (const float*)d_in[6];
    const float* bias    = (const float*)d_in[7];
    float* out = (float*)d_out;

    unsigned short* xt    = (unsigned short*)d_ws;                    // 2 MB (tiled)
    unsigned short* parts = (unsigned short*)((char*)d_ws
                            + (size_t)NROWS * IN_F * 2);              // 16 MB

    k_pre4<<<dim3(NROWS, 2), 256, 0, stream>>>(in, scaleWH, SU, xt);
    k_gemm7<<<dim3(OUT_F / NTB, NSL), 256, 0, stream>>>(xt, Qidxs, cb, wscale, parts);
    k_post4<<<dim3(NROWS, 2), 256, 0, stream>>>(parts, SV, bias, out);
}

// Round 12
// 46.319 us; speedup vs baseline: 1.1239x; 1.1239x over previous
//
#include <hip/hip_runtime.h>
#include <hip/hip_bf16.h>

#define IN_F 8192
#define OUT_F 8192
#define NROWS 128
#define CB 256
#define NSL 8                  // split-K slices
#define KSLICE (IN_F / NSL)    // 1024
#define NTB 128                // n-tile per block
#define QC (IN_F / 8)          // 1024 dwords per Qidxs row

using bf8   = __attribute__((ext_vector_type(8))) short;  // 8 bf16 (4 VGPRs)
using f32x4 = __attribute__((ext_vector_type(4))) float;  // 4 fp32 accum

typedef const __attribute__((address_space(1))) void* as1cv;
typedef __attribute__((address_space(3))) void* as3v;

__device__ inline float bf2f(unsigned int u) {
    union { unsigned int i; float f; } v; v.i = u << 16; return v.f;
}
__device__ inline unsigned short f2bf(float f) {
    __hip_bfloat16 h = __float2bfloat16(f);
    return *reinterpret_cast<unsigned short*>(&h);
}
__device__ inline void unpack8(uint4 v, float* f) {
    f[0] = bf2f(v.x & 0xffffu); f[1] = bf2f(v.x >> 16);
    f[2] = bf2f(v.y & 0xffffu); f[3] = bf2f(v.y >> 16);
    f[4] = bf2f(v.z & 0xffffu); f[5] = bf2f(v.z >> 16);
    f[6] = bf2f(v.w & 0xffffu); f[7] = bf2f(v.w >> 16);
}

#define FWHT_SCALE 0.011048543456039806f  // 1/sqrt(8192)

// ---------------- FWHT-4096 on 256 threads x 16 elems (round-11 proven) ----
#define FWHT16(v)                                                         \
    _Pragma("unroll")                                                     \
    for (int hb = 0; hb < 4; ++hb) {                                      \
        const int hh = 1 << hb;                                           \
        _Pragma("unroll")                                                 \
        for (int j = 0; j < 16; ++j)                                      \
            if (!(j & hh)) {                                              \
                float a_ = v[j], b_ = v[j | hh];                          \
                v[j] = a_ + b_; v[j | hh] = a_ - b_;                      \
            }                                                             \
    }

__device__ inline void fwht4096(float* v, float* lds, int t) {
    FWHT16(v)
#pragma unroll
    for (int e = 0; e < 16; ++e) lds[e * 260 + t] = v[e];
    __syncthreads();
    {
        const int base = (t & 15) * 260 + (t >> 4) * 16;
#pragma unroll
        for (int q = 0; q < 4; ++q) {
            float4 f = *reinterpret_cast<const float4*>(&lds[base + q * 4]);
            v[q * 4 + 0] = f.x; v[q * 4 + 1] = f.y;
            v[q * 4 + 2] = f.z; v[q * 4 + 3] = f.w;
        }
    }
    FWHT16(v)
    __syncthreads();
    {
        const int e = t & 15, ub = t >> 4;
#pragma unroll
        for (int i = 0; i < 16; ++i) lds[e * 260 + i * 16 + ub] = v[i];
    }
    __syncthreads();
    {
        const int e = t & 15, i = t >> 4;
#pragma unroll
        for (int ub = 0; ub < 16; ++ub) v[ub] = lds[e * 260 + i * 16 + ub];
    }
    FWHT16(v)
    __syncthreads();
    {
        const int e = t & 15, i = t >> 4;
#pragma unroll
        for (int ub = 0; ub < 16; ++ub) lds[ub * 260 + i * 16 + e] = v[ub];
    }
    __syncthreads();
    {
        const int base = (t >> 4) * 260 + (t & 15) * 16;
#pragma unroll
        for (int q = 0; q < 4; ++q) {
            float4 f = *reinterpret_cast<const float4*>(&lds[base + q * 4]);
            v[q * 4 + 0] = f.x; v[q * 4 + 1] = f.y;
            v[q * 4 + 2] = f.z; v[q * 4 + 3] = f.w;
        }
    }
}

// ---- Kernel A: xt = fwht(input/scaleWH*SU), MFMA-tiled bf16, grid (128,2) --
// Tiled layout: elem (r,k) at ((r>>4)*256 + (k>>5))*512 + ((k&31)>>3)*128
//               + (r&15)*8 + (k&7)   [ushort units]
__global__ __launch_bounds__(256) void k_pre4(const float* __restrict__ in,
                                              const float* __restrict__ scaleWH,
                                              const float* __restrict__ SU,
                                              unsigned short* __restrict__ xt) {
    __shared__ float lds[4160];
    const int r = blockIdx.x, h = blockIdx.y, t = threadIdx.x;
    float v[16];
    const float4* xp = reinterpret_cast<const float4*>(in + (size_t)r * IN_F);
    const float4* sp = reinterpret_cast<const float4*>(scaleWH);
    const float4* up = reinterpret_cast<const float4*>(SU);
#pragma unroll
    for (int q = 0; q < 4; ++q) {
        float4 xl = xp[t * 4 + q],        sl = sp[t * 4 + q],        ul = up[t * 4 + q];
        float4 xh = xp[1024 + t * 4 + q], sh = sp[1024 + t * 4 + q], uh = up[1024 + t * 4 + q];
        float lo0 = xl.x / sl.x * ul.x, hi0 = xh.x / sh.x * uh.x;
        float lo1 = xl.y / sl.y * ul.y, hi1 = xh.y / sh.y * uh.y;
        float lo2 = xl.z / sl.z * ul.z, hi2 = xh.z / sh.z * uh.z;
        float lo3 = xl.w / sl.w * ul.w, hi3 = xh.w / sh.w * uh.w;
        v[q * 4 + 0] = h ? lo0 - hi0 : lo0 + hi0;
        v[q * 4 + 1] = h ? lo1 - hi1 : lo1 + hi1;
        v[q * 4 + 2] = h ? lo2 - hi2 : lo2 + hi2;
        v[q * 4 + 3] = h ? lo3 - hi3 : lo3 + hi3;
    }
    fwht4096(v, lds, t);
    const int ub = t >> 4, i = t & 15;
    const int kblk = h * 128 + ub * 8 + (i >> 1);
    const size_t base = ((size_t)(r >> 4) * 256 + kblk) * 512 + (size_t)(r & 15) * 8;
#pragma unroll
    for (int half = 0; half < 2; ++half) {
        unsigned int w[4];
#pragma unroll
        for (int p = 0; p < 4; ++p) {
            unsigned int lo = f2bf(v[half * 8 + 2 * p]     * FWHT_SCALE);
            unsigned int hi = f2bf(v[half * 8 + 2 * p + 1] * FWHT_SCALE);
            w[p] = lo | (hi << 16);
        }
        const int oct = (i & 1) * 2 + half;
        *reinterpret_cast<uint4*>(xt + base + oct * 128) = make_uint4(w[0], w[1], w[2], w[3]);
    }
}

// ---- Kernel B: GEMM, 512 thr = 8 waves (4 wave-rows x 2 wave-cols) ----
// grid (64, NSL); block tile 128x128; K-step 32; A dup only 2x (L2 256MB).
// Qidxs chunks (128 x 64 dwords, 32KB) double-buffered via global_load_lds;
// barriers only at chunk boundaries (drain loads issued a full chunk ago).
__global__ __launch_bounds__(512, 4) void k_gemm9(
        const unsigned short* __restrict__ xt,
        const int* __restrict__ Qidxs,
        const float* __restrict__ cb,
        const float* __restrict__ wscale,
        unsigned short* __restrict__ pout) {
    __shared__ __align__(16) unsigned short cbl[CB][8];   // 4 KB
    __shared__ __align__(16) int Qlds[2][128 * 64];       // 2 x 32 KB
    const int tid = threadIdx.x;
    const int wave = tid >> 6, lane = tid & 63;
    const int wr = wave & 3, wc = wave >> 2;     // 4 wave-rows x 2 wave-cols
    const int lr = lane & 15, lk8 = lane >> 4;
    const int n0 = blockIdx.x * NTB;
    const int ks0 = blockIdx.y * KSLICE;
    const int ksb = ks0 >> 5;
    const int c0 = ks0 >> 3;

    // stage one 128-row x 64-dword Qidxs chunk. LDS dest linear in lane
    // (base + lane*16B covers (row=lane>>4, cg=lane&15)); global source
    // col-group pre-swizzled by (row & 15) for clean in-loop b32 reads.
    auto stageQ = [&](int buf, int ch) {
#pragma unroll
        for (int j = 0; j < 4; ++j) {
            const int row = j * 32 + wave * 4 + (lane >> 4);
            const int cgs = (lane & 15) ^ (row & 15);
            const int* g = Qidxs + (size_t)(n0 + row) * QC + c0 + ch * 64 + cgs * 4;
            as3v l = (as3v)(&Qlds[buf][(j * 32 + wave * 4) * 64]);
            __builtin_amdgcn_global_load_lds((as1cv)(const void*)g, l, 16, 0, 0);
        }
    };

    stageQ(0, 0);
    const float wsc = wscale[0];
    for (int e = tid; e < CB * 8; e += 512) cbl[e >> 3][e & 7] = f2bf(cb[e] * wsc);

    f32x4 acc[2][4];
#pragma unroll
    for (int mt = 0; mt < 2; ++mt)
#pragma unroll
        for (int nt = 0; nt < 4; ++nt) acc[mt][nt] = (f32x4){0.f, 0.f, 0.f, 0.f};

    // A (tiled layout): frag (m-block wr*2+mt, k-block ksb+it) contiguous 1KB
    const unsigned short* xw = xt + ((size_t)(wr * 2) * 256 + ksb) * 512 + lane * 8;
    __syncthreads();          // cbl + chunk 0 staged
    stageQ(1, 1);             // chunk 1 in flight across chunk 0 compute

#define CHUNK(BUF, CH)                                                        \
    _Pragma("unroll")                                                         \
    for (int itc = 0; itc < 16; ++itc) {                                      \
        const int it = (CH) * 16 + itc;                                       \
        const int qcol = ((itc ^ lr) << 2) + lk8;                             \
        const int qv0 = Qlds[BUF][(wc * 64 +  0 + lr) * 64 + qcol];           \
        const int qv1 = Qlds[BUF][(wc * 64 + 16 + lr) * 64 + qcol];           \
        const int qv2 = Qlds[BUF][(wc * 64 + 32 + lr) * 64 + qcol];           \
        const int qv3 = Qlds[BUF][(wc * 64 + 48 + lr) * 64 + qcol];           \
        bf8 a0 = *reinterpret_cast<const bf8*>(xw + ((size_t)(0 * 256) + it) * 512); \
        bf8 a1 = *reinterpret_cast<const bf8*>(xw + ((size_t)(1 * 256) + it) * 512); \
        bf8 b0 = *(const bf8*)&cbl[qv0][0];                                   \
        bf8 b1 = *(const bf8*)&cbl[qv1][0];                                   \
        bf8 b2 = *(const bf8*)&cbl[qv2][0];                                   \
        bf8 b3 = *(const bf8*)&cbl[qv3][0];                                   \
        acc[0][0] = __builtin_amdgcn_mfma_f32_16x16x32_bf16(a0, b0, acc[0][0], 0, 0, 0); \
        acc[0][1] = __builtin_amdgcn_mfma_f32_16x16x32_bf16(a0, b1, acc[0][1], 0, 0, 0); \
        acc[0][2] = __builtin_amdgcn_mfma_f32_16x16x32_bf16(a0, b2, acc[0][2], 0, 0, 0); \
        acc[0][3] = __builtin_amdgcn_mfma_f32_16x16x32_bf16(a0, b3, acc[0][3], 0, 0, 0); \
        acc[1][0] = __builtin_amdgcn_mfma_f32_16x16x32_bf16(a1, b0, acc[1][0], 0, 0, 0); \
        acc[1][1] = __builtin_amdgcn_mfma_f32_16x16x32_bf16(a1, b1, acc[1][1], 0, 0, 0); \
        acc[1][2] = __builtin_amdgcn_mfma_f32_16x16x32_bf16(a1, b2, acc[1][2], 0, 0, 0); \
        acc[1][3] = __builtin_amdgcn_mfma_f32_16x16x32_bf16(a1, b3, acc[1][3], 0, 0, 0); \
    }

    CHUNK(0, 0)
    __syncthreads();          // drains stage(1) — issued a full chunk ago
    CHUNK(1, 1)
#undef CHUNK

    // epilogue: C/D col=lane&15, row=(lane>>4)*4+reg; bf16 partial store
    unsigned short* ps = pout + (size_t)blockIdx.y * (NROWS * OUT_F);
#pragma unroll
    for (int mt = 0; mt < 2; ++mt) {
        const int row = wr * 32 + mt * 16 + lk8 * 4;
#pragma unroll
        for (int nt = 0; nt < 4; ++nt) {
            const int col = n0 + wc * 64 + nt * 16 + lr;
#pragma unroll
            for (int r2 = 0; r2 < 4; ++r2)
                ps[(size_t)(row + r2) * OUT_F + col] = f2bf(acc[mt][nt][r2]);
        }
    }
}

// ---- Kernel C: out = fwht(sum_slices)*SV + bias, grid (128,2), f32 out ----
__global__ __launch_bounds__(256) void k_post4(const unsigned short* __restrict__ pin,
                                               const float* __restrict__ SV,
                                               const float* __restrict__ bias,
                                               float* __restrict__ out) {
    __shared__ float lds[4160];
    const int r = blockIdx.x, h = blockIdx.y, t = threadIdx.x;
    float lo[16], hi[16], v[16];
#pragma unroll
    for (int j = 0; j < 16; ++j) { lo[j] = 0.f; hi[j] = 0.f; }
#pragma unroll 1
    for (int sl = 0; sl < NSL; ++sl) {
        const uint4* pl = reinterpret_cast<const uint4*>(
            pin + (size_t)sl * NROWS * OUT_F + (size_t)r * OUT_F + t * 16);
        const uint4* ph = reinterpret_cast<const uint4*>(
            pin + (size_t)sl * NROWS * OUT_F + (size_t)r * OUT_F + 4096 + t * 16);
        float a[8], b[8];
        unpack8(pl[0], a); unpack8(pl[1], b);
#pragma unroll
        for (int j = 0; j < 8; ++j) { lo[j] += a[j]; lo[8 + j] += b[j]; }
        unpack8(ph[0], a); unpack8(ph[1], b);
#pragma unroll
        for (int j = 0; j < 8; ++j) { hi[j] += a[j]; hi[8 + j] += b[j]; }
    }
#pragma unroll
    for (int j = 0; j < 16; ++j) v[j] = h ? lo[j] - hi[j] : lo[j] + hi[j];
    fwht4096(v, lds, t);
    const int cb4 = (h * 4096 + (t >> 4) * 256 + (t & 15) * 16) >> 2;
    const float4* svp = reinterpret_cast<const float4*>(SV);
    const float4* bip = reinterpret_cast<const float4*>(bias);
    float4* op = reinterpret_cast<float4*>(out + (size_t)r * OUT_F);
#pragma unroll
    for (int q = 0; q < 4; ++q) {
        float4 sv = svp[cb4 + q], bi = bip[cb4 + q], o;
        o.x = v[q * 4 + 0] * FWHT_SCALE * sv.x + bi.x;
        o.y = v[q * 4 + 1] * FWHT_SCALE * sv.y + bi.y;
        o.z = v[q * 4 + 2] * FWHT_SCALE * sv.z + bi.z;
        o.w = v[q * 4 + 3] * FWHT_SCALE * sv.w + bi.w;
        op[cb4 + q] = o;
    }
}

extern "C" void kernel_launch(void* const* d_in, const int* in_sizes, int n_in,
                              void* d_out, int out_size, void* d_ws, size_t ws_size,
                              hipStream_t stream) {
    const float* in      = (const float*)d_in[0];
    const int*   Qidxs   = (const int*)d_in[1];
    const float* cb      = (const float*)d_in[2];
    const float* scaleWH = (const float*)d_in[3];
    const float* SU      = (const float*)d_in[4];
    const float* SV      = (const float*)d_in[5];
    const float* wscale  = (const float*)d_in[6];
    const float* bias    = (const float*)d_in[7];
    float* out = (float*)d_out;

    unsigned short* xt    = (unsigned short*)d_ws;                    // 2 MB (tiled)
    unsigned short* parts = (unsigned short*)((char*)d_ws
                            + (size_t)NROWS * IN_F * 2);              // 16 MB

    k_pre4<<<dim3(NROWS, 2), 256, 0, stream>>>(in, scaleWH, SU, xt);
    k_gemm9<<<dim3(OUT_F / NTB, NSL), 512, 0, stream>>>(xt, Qidxs, cb, wscale, parts);
    k_post4<<<dim3(NROWS, 2), 256, 0, stream>>>(parts, SV, bias, out);
}